// Round 1
// baseline (2010.934 us; speedup 1.0000x reference)
//
#include <hip/hip_runtime.h>
#include <hip/hip_bf16.h>
#include <math.h>

#define TB 256

// hardware f32 atomic add (global_atomic_add_f32) — avoids CAS loop
__device__ __forceinline__ void atomic_add_f32(float* p, float v) {
    unsafeAtomicAdd(p, v);
}

// Zero deg (n_nodes), sums (256*32), cnt (256)
__global__ __launch_bounds__(TB) void zero_kernel(float* __restrict__ deg,
                                                  float* __restrict__ sums,
                                                  float* __restrict__ cnt,
                                                  int n_nodes) {
    int i = blockIdx.x * TB + threadIdx.x;
    if (i < n_nodes) deg[i] = 0.0f;
    if (i < 256 * 32) sums[i] = 0.0f;
    if (i < 256) cnt[i] = 0.0f;
}

// Per-edge Gaussian kernel weight + degree scatter
__global__ __launch_bounds__(TB) void edge_weight_kernel(
    const int* __restrict__ row, const int* __restrict__ col,
    const float2* __restrict__ pos2,
    const float* __restrict__ s1p, const float* __restrict__ s2p,
    float* __restrict__ ew, float* __restrict__ deg, int n_edges) {
    int e = blockIdx.x * TB + threadIdx.x;
    if (e >= n_edges) return;
    int r = row[e], c = col[e];
    // pos row layout: [p0 p1 p2 a0 a1 a2] -> float2 triplets
    float2 r0 = pos2[r * 3 + 0], r1 = pos2[r * 3 + 1], r2 = pos2[r * 3 + 2];
    float2 c0 = pos2[c * 3 + 0], c1 = pos2[c * 3 + 1], c2 = pos2[c * 3 + 2];
    float dx = r0.x - c0.x, dy = r0.y - c0.y, dz = r1.x - c1.x;
    float D = dx * dx + dy * dy + dz * dz;
    float dot = r1.y * c1.y + r2.x * c2.x + r2.y * c2.y;
    float t = 1.0f - dot;
    float T = t * t;
    float s1 = s1p[0], s2 = s2p[0];
    float w = expf(-(D * s1 * s1 + T * s2 * s2));
    ew[e] = w;
    atomic_add_f32(&deg[c], w);
}

// dinv = (deg+1)^-0.5, in place
__global__ __launch_bounds__(TB) void dinv_kernel(float* __restrict__ deg, int n) {
    int i = blockIdx.x * TB + threadIdx.x;
    if (i < n) deg[i] = 1.0f / sqrtf(deg[i] + 1.0f);
}

// norm = dinv[row]*ew*dinv[col], in place on ew
__global__ __launch_bounds__(TB) void norm_kernel(
    const int* __restrict__ row, const int* __restrict__ col,
    const float* __restrict__ dinv, float* __restrict__ ew, int n_edges) {
    int e = blockIdx.x * TB + threadIdx.x;
    if (e >= n_edges) return;
    ew[e] = dinv[row[e]] * ew[e] * dinv[col[e]];
}

// Dense matmul fin(N x K) @ W(K x 32) -> xw(N x 32); optional fused BN+ReLU on input
template <int K, bool BN>
__global__ __launch_bounds__(TB) void matmul_kernel(
    const float* __restrict__ fin, const float* __restrict__ W,
    const float* __restrict__ g, const float* __restrict__ be,
    float* __restrict__ xw, int n_nodes) {
    __shared__ float Ws[K * 32];
    __shared__ float gs[32];
    __shared__ float bs[32];
    int tid = threadIdx.x;
    for (int i = tid; i < K * 32; i += TB) Ws[i] = W[i];
    if (BN) {
        if (tid < 32) {
            gs[tid] = g[tid] * (1.0f / sqrtf(1.0f + 1e-5f));
            bs[tid] = be[tid];
        }
    }
    __syncthreads();
    int n = blockIdx.x * TB + tid;
    if (n >= n_nodes) return;
    float vals[K];
    const float* fp = fin + (size_t)n * K;
    if (K % 4 == 0) {
#pragma unroll
        for (int k = 0; k < K / 4; k++) {
            float4 v = ((const float4*)fp)[k];
            vals[k * 4 + 0] = v.x;
            vals[k * 4 + 1] = v.y;
            vals[k * 4 + 2] = v.z;
            vals[k * 4 + 3] = v.w;
        }
    } else {
#pragma unroll
        for (int k = 0; k < K; k++) vals[k] = fp[k];
    }
    if (BN) {
#pragma unroll
        for (int k = 0; k < K; k++) vals[k] = fmaxf(fmaf(vals[k], gs[k], bs[k]), 0.0f);
    }
    float acc[32];
#pragma unroll
    for (int j = 0; j < 32; j++) acc[j] = 0.0f;
#pragma unroll
    for (int k = 0; k < K; k++) {
        float v = vals[k];
#pragma unroll
        for (int j = 0; j < 32; j++) acc[j] = fmaf(v, Ws[k * 32 + j], acc[j]);
    }
    float4* op = (float4*)(xw + (size_t)n * 32);
#pragma unroll
    for (int j = 0; j < 8; j++)
        op[j] = make_float4(acc[j * 4], acc[j * 4 + 1], acc[j * 4 + 2], acc[j * 4 + 3]);
}

// agg[n][j] = dinv[n]^2 * xw[n][j] + b[j]  (full overwrite — init for scatter)
__global__ __launch_bounds__(TB) void node_init_kernel(
    const float* __restrict__ xw, const float* __restrict__ dinv,
    const float* __restrict__ b, float* __restrict__ agg, int n_nodes) {
    int idx = blockIdx.x * TB + threadIdx.x;
    if (idx >= n_nodes * 32) return;
    int n = idx >> 5, j = idx & 31;
    float di = dinv[n];
    agg[idx] = di * di * xw[idx] + b[j];
}

// agg[col] += norm[e] * xw[row]  — 32 lanes per edge (one per feature)
__global__ __launch_bounds__(TB) void edge_scatter_kernel(
    const int* __restrict__ row, const int* __restrict__ col,
    const float* __restrict__ norm, const float* __restrict__ xw,
    float* __restrict__ agg, int n_edges) {
    int tid = blockIdx.x * TB + threadIdx.x;
    int e = tid >> 5;
    int j = tid & 31;
    if (e >= n_edges) return;
    int r = row[e], c = col[e];
    float v = norm[e] * xw[r * 32 + j];
    atomic_add_f32(&agg[c * 32 + j], v);
}

// Write emb to d_out, accumulate per-graph sums and counts
__global__ __launch_bounds__(TB) void pool_kernel(
    const float* __restrict__ agg, const int* __restrict__ batch,
    float* __restrict__ out_emb, float* __restrict__ sums,
    float* __restrict__ cnt, int n_nodes) {
    int idx = blockIdx.x * TB + threadIdx.x;
    if (idx >= n_nodes * 32) return;
    int n = idx >> 5, j = idx & 31;
    float v = agg[idx];
    out_emb[idx] = v;
    int b = batch[n];
    atomic_add_f32(&sums[b * 32 + j], v);
    if (j == 0) atomic_add_f32(&cnt[b], 1.0f);
}

// pred[g] = sigmoid(dot(sums[g]/max(cnt,1), Wout) + bout)
__global__ __launch_bounds__(TB) void pred_kernel(
    const float* __restrict__ sums, const float* __restrict__ cnt,
    const float* __restrict__ Wout, const float* __restrict__ bout,
    float* __restrict__ out) {
    int g = blockIdx.x * TB + threadIdx.x;
    if (g >= 256) return;
    float c = fmaxf(cnt[g], 1.0f);
    float acc = 0.0f;
#pragma unroll
    for (int j = 0; j < 32; j++) acc += sums[g * 32 + j] * Wout[j];
    float z = acc / c + bout[0];
    out[g] = 1.0f / (1.0f + expf(-z));
}

extern "C" void kernel_launch(void* const* d_in, const int* in_sizes, int n_in,
                              void* d_out, int out_size, void* d_ws, size_t ws_size,
                              hipStream_t stream) {
    // Input order per setup_inputs():
    const float* x = (const float*)d_in[0];           // (N, 6)
    const int* edge_index = (const int*)d_in[1];      // (2, E)
    const float* pos = (const float*)d_in[2];         // (N, 6)
    const int* batch = (const int*)d_in[3];           // (N,)
    const float* s1 = (const float*)d_in[4];
    const float* s2 = (const float*)d_in[5];
    const float* W1 = (const float*)d_in[6];
    const float* b1 = (const float*)d_in[7];
    const float* W2 = (const float*)d_in[8];
    const float* b2 = (const float*)d_in[9];
    const float* W3 = (const float*)d_in[10];
    const float* b3 = (const float*)d_in[11];
    const float* W4 = (const float*)d_in[12];
    const float* b4 = (const float*)d_in[13];
    const float* g1 = (const float*)d_in[14];
    const float* be1 = (const float*)d_in[15];
    const float* g2 = (const float*)d_in[16];
    const float* be2 = (const float*)d_in[17];
    const float* g3 = (const float*)d_in[18];
    const float* be3 = (const float*)d_in[19];
    const float* Wout = (const float*)d_in[20];
    const float* bout = (const float*)d_in[21];

    const size_t E = (size_t)in_sizes[1] / 2;
    const size_t N = (size_t)in_sizes[3];

    const int* row = edge_index;
    const int* col = edge_index + E;

    // Workspace carve-up (all offsets 256B-aligned)
    auto align256 = [](size_t v) { return (v + 255) & ~(size_t)255; };
    char* w = (char*)d_ws;
    float* norm = (float*)w; w += align256(E * 4);
    float* dinv = (float*)w; w += align256(N * 4);   // deg then dinv in place
    float* bufA = (float*)w; w += align256(N * 32 * 4);
    float* bufB = (float*)w; w += align256(N * 32 * 4);
    float* sums = (float*)w; w += align256(256 * 32 * 4);
    float* cnt = (float*)w;  w += align256(256 * 4);

    float* out_emb = (float*)d_out;
    float* out_pred = (float*)d_out + N * 32;

    const int gN = (int)((N + TB - 1) / TB);
    const int gE = (int)((E + TB - 1) / TB);
    const int gN32 = (int)((N * 32 + TB - 1) / TB);
    const int gE32 = (int)((E * 32 + TB - 1) / TB);

    zero_kernel<<<gN, TB, 0, stream>>>(dinv, sums, cnt, (int)N);
    edge_weight_kernel<<<gE, TB, 0, stream>>>(row, col, (const float2*)pos, s1, s2,
                                              norm, dinv, (int)E);
    dinv_kernel<<<gN, TB, 0, stream>>>(dinv, (int)N);
    norm_kernel<<<gE, TB, 0, stream>>>(row, col, dinv, norm, (int)E);

    // Layer 1: x (N,6) -> bufA; agg into bufB
    matmul_kernel<6, false><<<gN, TB, 0, stream>>>(x, W1, nullptr, nullptr, bufA, (int)N);
    node_init_kernel<<<gN32, TB, 0, stream>>>(bufA, dinv, b1, bufB, (int)N);
    edge_scatter_kernel<<<gE32, TB, 0, stream>>>(row, col, norm, bufA, bufB, (int)E);

    // Layer 2: relu(bn1(bufB)) @ W2 -> bufA; agg into bufB
    matmul_kernel<32, true><<<gN, TB, 0, stream>>>(bufB, W2, g1, be1, bufA, (int)N);
    node_init_kernel<<<gN32, TB, 0, stream>>>(bufA, dinv, b2, bufB, (int)N);
    edge_scatter_kernel<<<gE32, TB, 0, stream>>>(row, col, norm, bufA, bufB, (int)E);

    // Layer 3
    matmul_kernel<32, true><<<gN, TB, 0, stream>>>(bufB, W3, g2, be2, bufA, (int)N);
    node_init_kernel<<<gN32, TB, 0, stream>>>(bufA, dinv, b3, bufB, (int)N);
    edge_scatter_kernel<<<gE32, TB, 0, stream>>>(row, col, norm, bufA, bufB, (int)E);

    // Layer 4 (no BN on output; BN3 fused on input)
    matmul_kernel<32, true><<<gN, TB, 0, stream>>>(bufB, W4, g3, be3, bufA, (int)N);
    node_init_kernel<<<gN32, TB, 0, stream>>>(bufA, dinv, b4, bufB, (int)N);
    edge_scatter_kernel<<<gE32, TB, 0, stream>>>(row, col, norm, bufA, bufB, (int)E);

    // Pooling + head
    pool_kernel<<<gN32, TB, 0, stream>>>(bufB, batch, out_emb, sums, cnt, (int)N);
    pred_kernel<<<1, TB, 0, stream>>>(sums, cnt, Wout, bout, out_pred);
}

// Round 2
// 1547.330 us; speedup vs baseline: 1.2996x; 1.2996x over previous
//
#include <hip/hip_runtime.h>
#include <hip/hip_bf16.h>
#include <math.h>

#define TB 256
#define SCAN_T 1024

__device__ __forceinline__ void atomic_add_f32(float* p, float v) {
    unsafeAtomicAdd(p, v);  // hardware global_atomic_add_f32
}

// Zero deg (N), hist (N), sums (256*32), cnt (256)
__global__ __launch_bounds__(TB) void zero_kernel(float* __restrict__ deg,
                                                  int* __restrict__ hist,
                                                  float* __restrict__ sums,
                                                  float* __restrict__ cnt,
                                                  int n_nodes) {
    int i = blockIdx.x * TB + threadIdx.x;
    if (i < n_nodes) { deg[i] = 0.0f; hist[i] = 0; }
    if (i < 256 * 32) sums[i] = 0.0f;
    if (i < 256) cnt[i] = 0.0f;
}

// Per-edge Gaussian weight + degree scatter + col histogram
__global__ __launch_bounds__(TB) void edge_weight_kernel(
    const int* __restrict__ row, const int* __restrict__ col,
    const float2* __restrict__ pos2,
    const float* __restrict__ s1p, const float* __restrict__ s2p,
    float* __restrict__ ew, float* __restrict__ deg, int* __restrict__ hist,
    int n_edges) {
    int e = blockIdx.x * TB + threadIdx.x;
    if (e >= n_edges) return;
    int r = row[e], c = col[e];
    float2 r0 = pos2[r * 3 + 0], r1 = pos2[r * 3 + 1], r2 = pos2[r * 3 + 2];
    float2 c0 = pos2[c * 3 + 0], c1 = pos2[c * 3 + 1], c2 = pos2[c * 3 + 2];
    float dx = r0.x - c0.x, dy = r0.y - c0.y, dz = r1.x - c1.x;
    float D = dx * dx + dy * dy + dz * dz;
    float dot = r1.y * c1.y + r2.x * c2.x + r2.y * c2.y;
    float t = 1.0f - dot;
    float T = t * t;
    float s1 = s1p[0], s2 = s2p[0];
    float w = expf(-(D * s1 * s1 + T * s2 * s2));
    ew[e] = w;
    atomic_add_f32(&deg[c], w);
    atomicAdd(&hist[c], 1);
}

// dinv = (deg+1)^-0.5, in place
__global__ __launch_bounds__(TB) void dinv_kernel(float* __restrict__ deg, int n) {
    int i = blockIdx.x * TB + threadIdx.x;
    if (i < n) deg[i] = 1.0f / sqrtf(deg[i] + 1.0f);
}

// Single-block exclusive scan: hist[0..n) -> ptr[0..n], cursor copy
__global__ __launch_bounds__(SCAN_T) void scan_kernel(const int* __restrict__ hist,
                                                      int* __restrict__ ptr,
                                                      int* __restrict__ cursor, int n) {
    __shared__ int part[SCAN_T];
    int t = threadIdx.x;
    int chunk = (n + SCAN_T - 1) / SCAN_T;
    int beg = t * chunk;
    int end = min(beg + chunk, n);
    int s = 0;
    for (int i = beg; i < end; i++) s += hist[i];
    part[t] = s;
    __syncthreads();
    for (int off = 1; off < SCAN_T; off <<= 1) {
        int v = (t >= off) ? part[t - off] : 0;
        __syncthreads();
        part[t] += v;
        __syncthreads();
    }
    int run = (t == 0) ? 0 : part[t - 1];
    for (int i = beg; i < end; i++) {
        ptr[i] = run;
        cursor[i] = run;
        run += hist[i];
    }
    if (t == SCAN_T - 1) ptr[n] = part[SCAN_T - 1];
}

// Scatter edges into CSR slots; entry = {row, bits(norm)}
__global__ __launch_bounds__(TB) void fill_kernel(
    const int* __restrict__ row, const int* __restrict__ col,
    const float* __restrict__ ew, const float* __restrict__ dinv,
    int* __restrict__ cursor, int2* __restrict__ csr, int n_edges) {
    int e = blockIdx.x * TB + threadIdx.x;
    if (e >= n_edges) return;
    int r = row[e], c = col[e];
    float nm = dinv[r] * ew[e] * dinv[c];
    int pos = atomicAdd(&cursor[c], 1);
    csr[pos] = make_int2(r, __float_as_int(nm));
}

// Dense matmul fin(N x K) @ W(K x 32) -> xw(N x 32); optional fused BN+ReLU on input
template <int K, bool BN>
__global__ __launch_bounds__(TB) void matmul_kernel(
    const float* __restrict__ fin, const float* __restrict__ W,
    const float* __restrict__ g, const float* __restrict__ be,
    float* __restrict__ xw, int n_nodes) {
    __shared__ float Ws[K * 32];
    __shared__ float gs[32];
    __shared__ float bs[32];
    int tid = threadIdx.x;
    for (int i = tid; i < K * 32; i += TB) Ws[i] = W[i];
    if (BN) {
        if (tid < 32) {
            gs[tid] = g[tid] * (1.0f / sqrtf(1.0f + 1e-5f));
            bs[tid] = be[tid];
        }
    }
    __syncthreads();
    int n = blockIdx.x * TB + tid;
    if (n >= n_nodes) return;
    float vals[K];
    const float* fp = fin + (size_t)n * K;
    if (K % 4 == 0) {
#pragma unroll
        for (int k = 0; k < K / 4; k++) {
            float4 v = ((const float4*)fp)[k];
            vals[k * 4 + 0] = v.x;
            vals[k * 4 + 1] = v.y;
            vals[k * 4 + 2] = v.z;
            vals[k * 4 + 3] = v.w;
        }
    } else {
#pragma unroll
        for (int k = 0; k < K; k++) vals[k] = fp[k];
    }
    if (BN) {
#pragma unroll
        for (int k = 0; k < K; k++) vals[k] = fmaxf(fmaf(vals[k], gs[k], bs[k]), 0.0f);
    }
    float acc[32];
#pragma unroll
    for (int j = 0; j < 32; j++) acc[j] = 0.0f;
#pragma unroll
    for (int k = 0; k < K; k++) {
        float v = vals[k];
#pragma unroll
        for (int j = 0; j < 32; j++) acc[j] = fmaf(v, Ws[k * 32 + j], acc[j]);
    }
    float4* op = (float4*)(xw + (size_t)n * 32);
#pragma unroll
    for (int j = 0; j < 8; j++)
        op[j] = make_float4(acc[j * 4], acc[j * 4 + 1], acc[j * 4 + 2], acc[j * 4 + 3]);
}

// Per-node gather aggregation: agg[n] = b + dinv[n]^2*xw[n] + sum_e norm_e * xw[row_e]
// 32 lanes per node (one per feature). POOL: also do graph pooling atomics.
template <bool POOL>
__global__ __launch_bounds__(TB) void gather_kernel(
    const int* __restrict__ ptr, const int2* __restrict__ csr,
    const float* __restrict__ xw, const float* __restrict__ dinv,
    const float* __restrict__ b, const int* __restrict__ batch,
    float* __restrict__ agg, float* __restrict__ sums, float* __restrict__ cnt,
    int n_nodes) {
    int t = blockIdx.x * TB + threadIdx.x;
    int n = t >> 5, j = t & 31;
    if (n >= n_nodes) return;
    int beg = ptr[n], end = ptr[n + 1];
    float acc = 0.0f;
    int k = beg;
    for (; k + 1 < end; k += 2) {
        int2 p0 = csr[k];
        int2 p1 = csr[k + 1];
        float v0 = xw[(size_t)p0.x * 32 + j];
        float v1 = xw[(size_t)p1.x * 32 + j];
        acc = fmaf(__int_as_float(p0.y), v0, acc);
        acc = fmaf(__int_as_float(p1.y), v1, acc);
    }
    if (k < end) {
        int2 p0 = csr[k];
        acc = fmaf(__int_as_float(p0.y), xw[(size_t)p0.x * 32 + j], acc);
    }
    float di = dinv[n];
    float v = fmaf(di * di, xw[(size_t)n * 32 + j], acc) + b[j];
    agg[(size_t)n * 32 + j] = v;
    if (POOL) {
        int bg = batch[n];
        atomic_add_f32(&sums[bg * 32 + j], v);
        if (j == 0) atomic_add_f32(&cnt[bg], 1.0f);
    }
}

// pred[g] = sigmoid(dot(sums[g]/max(cnt,1), Wout) + bout)
__global__ __launch_bounds__(TB) void pred_kernel(
    const float* __restrict__ sums, const float* __restrict__ cnt,
    const float* __restrict__ Wout, const float* __restrict__ bout,
    float* __restrict__ out) {
    int g = blockIdx.x * TB + threadIdx.x;
    if (g >= 256) return;
    float c = fmaxf(cnt[g], 1.0f);
    float acc = 0.0f;
#pragma unroll
    for (int j = 0; j < 32; j++) acc += sums[g * 32 + j] * Wout[j];
    float z = acc / c + bout[0];
    out[g] = 1.0f / (1.0f + expf(-z));
}

extern "C" void kernel_launch(void* const* d_in, const int* in_sizes, int n_in,
                              void* d_out, int out_size, void* d_ws, size_t ws_size,
                              hipStream_t stream) {
    const float* x = (const float*)d_in[0];           // (N, 6)
    const int* edge_index = (const int*)d_in[1];      // (2, E)
    const float* pos = (const float*)d_in[2];         // (N, 6)
    const int* batch = (const int*)d_in[3];           // (N,)
    const float* s1 = (const float*)d_in[4];
    const float* s2 = (const float*)d_in[5];
    const float* W1 = (const float*)d_in[6];
    const float* b1 = (const float*)d_in[7];
    const float* W2 = (const float*)d_in[8];
    const float* b2 = (const float*)d_in[9];
    const float* W3 = (const float*)d_in[10];
    const float* b3 = (const float*)d_in[11];
    const float* W4 = (const float*)d_in[12];
    const float* b4 = (const float*)d_in[13];
    const float* g1 = (const float*)d_in[14];
    const float* be1 = (const float*)d_in[15];
    const float* g2 = (const float*)d_in[16];
    const float* be2 = (const float*)d_in[17];
    const float* g3 = (const float*)d_in[18];
    const float* be3 = (const float*)d_in[19];
    const float* Wout = (const float*)d_in[20];
    const float* bout = (const float*)d_in[21];

    const size_t E = (size_t)in_sizes[1] / 2;
    const size_t N = (size_t)in_sizes[3];

    const int* row = edge_index;
    const int* col = edge_index + E;

    auto align256 = [](size_t v) { return (v + 255) & ~(size_t)255; };
    char* w = (char*)d_ws;
    int2* csr = (int2*)w;    w += align256(E * 8);
    float* bufA = (float*)w; w += align256(N * 32 * 4);  // also aliases ew (E*4 <= N*32*4)
    float* bufB = (float*)w; w += align256(N * 32 * 4);
    float* dinv = (float*)w; w += align256(N * 4);       // deg then dinv in place
    int* hist = (int*)w;     w += align256(N * 4);
    int* ptr = (int*)w;      w += align256((N + 1) * 4);
    int* cursor = (int*)w;   w += align256(N * 4);
    float* sums = (float*)w; w += align256(256 * 32 * 4);
    float* cnt = (float*)w;  w += align256(256 * 4);
    float* ew = bufA;  // dead after fill_kernel; bufA first written by matmul1 (after fill)

    float* out_emb = (float*)d_out;
    float* out_pred = (float*)d_out + N * 32;

    const int gN = (int)((N + TB - 1) / TB);
    const int gE = (int)((E + TB - 1) / TB);
    const int gN32 = (int)((N * 32 + TB - 1) / TB);

    zero_kernel<<<gN, TB, 0, stream>>>(dinv, hist, sums, cnt, (int)N);
    edge_weight_kernel<<<gE, TB, 0, stream>>>(row, col, (const float2*)pos, s1, s2,
                                              ew, dinv, hist, (int)E);
    dinv_kernel<<<gN, TB, 0, stream>>>(dinv, (int)N);
    scan_kernel<<<1, SCAN_T, 0, stream>>>(hist, ptr, cursor, (int)N);
    fill_kernel<<<gE, TB, 0, stream>>>(row, col, ew, dinv, cursor, csr, (int)E);

    // Layer 1: x (N,6) @ W1 -> bufA; gather -> bufB
    matmul_kernel<6, false><<<gN, TB, 0, stream>>>(x, W1, nullptr, nullptr, bufA, (int)N);
    gather_kernel<false><<<gN32, TB, 0, stream>>>(ptr, csr, bufA, dinv, b1, batch,
                                                  bufB, sums, cnt, (int)N);
    // Layer 2
    matmul_kernel<32, true><<<gN, TB, 0, stream>>>(bufB, W2, g1, be1, bufA, (int)N);
    gather_kernel<false><<<gN32, TB, 0, stream>>>(ptr, csr, bufA, dinv, b2, batch,
                                                  bufB, sums, cnt, (int)N);
    // Layer 3
    matmul_kernel<32, true><<<gN, TB, 0, stream>>>(bufB, W3, g2, be2, bufA, (int)N);
    gather_kernel<false><<<gN32, TB, 0, stream>>>(ptr, csr, bufA, dinv, b3, batch,
                                                  bufB, sums, cnt, (int)N);
    // Layer 4: gather writes emb to d_out and does pooling
    matmul_kernel<32, true><<<gN, TB, 0, stream>>>(bufB, W4, g3, be3, bufA, (int)N);
    gather_kernel<true><<<gN32, TB, 0, stream>>>(ptr, csr, bufA, dinv, b4, batch,
                                                 out_emb, sums, cnt, (int)N);

    pred_kernel<<<1, TB, 0, stream>>>(sums, cnt, Wout, bout, out_pred);
}

// Round 3
// 1511.717 us; speedup vs baseline: 1.3302x; 1.0236x over previous
//
#include <hip/hip_runtime.h>
#include <hip/hip_bf16.h>
#include <math.h>

#define TB 256
#define SCAN_T 1024

__device__ __forceinline__ void atomic_add_f32(float* p, float v) {
    unsafeAtomicAdd(p, v);  // hardware global_atomic_add_f32
}

// Zero deg (N), hist (N), sums (256*32), cnt (256)
__global__ __launch_bounds__(TB) void zero_kernel(float* __restrict__ deg,
                                                  int* __restrict__ hist,
                                                  float* __restrict__ sums,
                                                  float* __restrict__ cnt,
                                                  int n_nodes) {
    int i = blockIdx.x * TB + threadIdx.x;
    if (i < n_nodes) { deg[i] = 0.0f; hist[i] = 0; }
    if (i < 256 * 32) sums[i] = 0.0f;
    if (i < 256) cnt[i] = 0.0f;
}

// Per-edge Gaussian weight + degree scatter + col histogram
__global__ __launch_bounds__(TB) void edge_weight_kernel(
    const int* __restrict__ row, const int* __restrict__ col,
    const float2* __restrict__ pos2,
    const float* __restrict__ s1p, const float* __restrict__ s2p,
    float* __restrict__ ew, float* __restrict__ deg, int* __restrict__ hist,
    int n_edges) {
    int e = blockIdx.x * TB + threadIdx.x;
    if (e >= n_edges) return;
    int r = row[e], c = col[e];
    float2 r0 = pos2[r * 3 + 0], r1 = pos2[r * 3 + 1], r2 = pos2[r * 3 + 2];
    float2 c0 = pos2[c * 3 + 0], c1 = pos2[c * 3 + 1], c2 = pos2[c * 3 + 2];
    float dx = r0.x - c0.x, dy = r0.y - c0.y, dz = r1.x - c1.x;
    float D = dx * dx + dy * dy + dz * dz;
    float dot = r1.y * c1.y + r2.x * c2.x + r2.y * c2.y;
    float t = 1.0f - dot;
    float T = t * t;
    float s1 = s1p[0], s2 = s2p[0];
    float w = expf(-(D * s1 * s1 + T * s2 * s2));
    ew[e] = w;
    atomic_add_f32(&deg[c], w);
    atomicAdd(&hist[c], 1);
}

// dinv = (deg+1)^-0.5, in place
__global__ __launch_bounds__(TB) void dinv_kernel(float* __restrict__ deg, int n) {
    int i = blockIdx.x * TB + threadIdx.x;
    if (i < n) deg[i] = 1.0f / sqrtf(deg[i] + 1.0f);
}

// Single-block exclusive scan: hist[0..n) -> ptr[0..n], cursor copy
__global__ __launch_bounds__(SCAN_T) void scan_kernel(const int* __restrict__ hist,
                                                      int* __restrict__ ptr,
                                                      int* __restrict__ cursor, int n) {
    __shared__ int part[SCAN_T];
    int t = threadIdx.x;
    int chunk = (n + SCAN_T - 1) / SCAN_T;
    int beg = t * chunk;
    int end = min(beg + chunk, n);
    int s = 0;
    for (int i = beg; i < end; i++) s += hist[i];
    part[t] = s;
    __syncthreads();
    for (int off = 1; off < SCAN_T; off <<= 1) {
        int v = (t >= off) ? part[t - off] : 0;
        __syncthreads();
        part[t] += v;
        __syncthreads();
    }
    int run = (t == 0) ? 0 : part[t - 1];
    for (int i = beg; i < end; i++) {
        ptr[i] = run;
        cursor[i] = run;
        run += hist[i];
    }
    if (t == SCAN_T - 1) ptr[n] = part[SCAN_T - 1];
}

// Scatter edges into CSR slots; split arrays: rows[] and norms[]
__global__ __launch_bounds__(TB) void fill_kernel(
    const int* __restrict__ row, const int* __restrict__ col,
    const float* __restrict__ ew, const float* __restrict__ dinv,
    int* __restrict__ cursor, int* __restrict__ rows, float* __restrict__ norms,
    int n_edges) {
    int e = blockIdx.x * TB + threadIdx.x;
    if (e >= n_edges) return;
    int r = row[e], c = col[e];
    float nm = dinv[r] * ew[e] * dinv[c];
    int pos = atomicAdd(&cursor[c], 1);
    rows[pos] = r;
    norms[pos] = nm;
}

// Dense matmul fin(N x K) @ W(K x 32) -> xw(N x 32); optional fused BN+ReLU on input
template <int K, bool BN>
__global__ __launch_bounds__(TB) void matmul_kernel(
    const float* __restrict__ fin, const float* __restrict__ W,
    const float* __restrict__ g, const float* __restrict__ be,
    float* __restrict__ xw, int n_nodes) {
    __shared__ float Ws[K * 32];
    __shared__ float gs[32];
    __shared__ float bs[32];
    int tid = threadIdx.x;
    for (int i = tid; i < K * 32; i += TB) Ws[i] = W[i];
    if (BN) {
        if (tid < 32) {
            gs[tid] = g[tid] * (1.0f / sqrtf(1.0f + 1e-5f));
            bs[tid] = be[tid];
        }
    }
    __syncthreads();
    int n = blockIdx.x * TB + tid;
    if (n >= n_nodes) return;
    float vals[K];
    const float* fp = fin + (size_t)n * K;
    if (K % 4 == 0) {
#pragma unroll
        for (int k = 0; k < K / 4; k++) {
            float4 v = ((const float4*)fp)[k];
            vals[k * 4 + 0] = v.x;
            vals[k * 4 + 1] = v.y;
            vals[k * 4 + 2] = v.z;
            vals[k * 4 + 3] = v.w;
        }
    } else {
#pragma unroll
        for (int k = 0; k < K; k++) vals[k] = fp[k];
    }
    if (BN) {
#pragma unroll
        for (int k = 0; k < K; k++) vals[k] = fmaxf(fmaf(vals[k], gs[k], bs[k]), 0.0f);
    }
    float acc[32];
#pragma unroll
    for (int j = 0; j < 32; j++) acc[j] = 0.0f;
#pragma unroll
    for (int k = 0; k < K; k++) {
        float v = vals[k];
#pragma unroll
        for (int j = 0; j < 32; j++) acc[j] = fmaf(v, Ws[k * 32 + j], acc[j]);
    }
    float4* op = (float4*)(xw + (size_t)n * 32);
#pragma unroll
    for (int j = 0; j < 8; j++)
        op[j] = make_float4(acc[j * 4], acc[j * 4 + 1], acc[j * 4 + 2], acc[j * 4 + 3]);
}

// Per-node gather: agg[n] = b + dinv[n]^2*xw[n] + sum_e norm_e * xw[row_e]
// 32 lanes per node (one per feature). Edge loop batched x8 for MLP:
// 8 independent index/weight loads -> 8 independent 128B gathers in flight.
template <bool POOL>
__global__ __launch_bounds__(TB) void gather_kernel(
    const int* __restrict__ ptr, const int* __restrict__ rows,
    const float* __restrict__ norms,
    const float* __restrict__ xw, const float* __restrict__ dinv,
    const float* __restrict__ b, const int* __restrict__ batch,
    float* __restrict__ agg, float* __restrict__ sums, float* __restrict__ cnt,
    int n_nodes) {
    int t = blockIdx.x * TB + threadIdx.x;
    int n = t >> 5, j = t & 31;
    if (n >= n_nodes) return;
    int beg = ptr[n], end = ptr[n + 1];
    float acc = 0.0f;
    int k = beg;
    for (; k + 8 <= end; k += 8) {
        int r0 = rows[k + 0], r1 = rows[k + 1], r2 = rows[k + 2], r3 = rows[k + 3];
        int r4 = rows[k + 4], r5 = rows[k + 5], r6 = rows[k + 6], r7 = rows[k + 7];
        float w0 = norms[k + 0], w1 = norms[k + 1], w2 = norms[k + 2], w3 = norms[k + 3];
        float w4 = norms[k + 4], w5 = norms[k + 5], w6 = norms[k + 6], w7 = norms[k + 7];
        float v0 = xw[(size_t)r0 * 32 + j];
        float v1 = xw[(size_t)r1 * 32 + j];
        float v2 = xw[(size_t)r2 * 32 + j];
        float v3 = xw[(size_t)r3 * 32 + j];
        float v4 = xw[(size_t)r4 * 32 + j];
        float v5 = xw[(size_t)r5 * 32 + j];
        float v6 = xw[(size_t)r6 * 32 + j];
        float v7 = xw[(size_t)r7 * 32 + j];
        acc = fmaf(w0, v0, acc);
        acc = fmaf(w1, v1, acc);
        acc = fmaf(w2, v2, acc);
        acc = fmaf(w3, v3, acc);
        acc = fmaf(w4, v4, acc);
        acc = fmaf(w5, v5, acc);
        acc = fmaf(w6, v6, acc);
        acc = fmaf(w7, v7, acc);
    }
    for (; k < end; k++) {
        int r = rows[k];
        float wv = norms[k];
        acc = fmaf(wv, xw[(size_t)r * 32 + j], acc);
    }
    float di = dinv[n];
    float v = fmaf(di * di, xw[(size_t)n * 32 + j], acc) + b[j];
    agg[(size_t)n * 32 + j] = v;
    if (POOL) {
        int bg = batch[n];
        atomic_add_f32(&sums[bg * 32 + j], v);
        if (j == 0) atomic_add_f32(&cnt[bg], 1.0f);
    }
}

// pred[g] = sigmoid(dot(sums[g]/max(cnt,1), Wout) + bout)
__global__ __launch_bounds__(TB) void pred_kernel(
    const float* __restrict__ sums, const float* __restrict__ cnt,
    const float* __restrict__ Wout, const float* __restrict__ bout,
    float* __restrict__ out) {
    int g = blockIdx.x * TB + threadIdx.x;
    if (g >= 256) return;
    float c = fmaxf(cnt[g], 1.0f);
    float acc = 0.0f;
#pragma unroll
    for (int j = 0; j < 32; j++) acc += sums[g * 32 + j] * Wout[j];
    float z = acc / c + bout[0];
    out[g] = 1.0f / (1.0f + expf(-z));
}

extern "C" void kernel_launch(void* const* d_in, const int* in_sizes, int n_in,
                              void* d_out, int out_size, void* d_ws, size_t ws_size,
                              hipStream_t stream) {
    const float* x = (const float*)d_in[0];           // (N, 6)
    const int* edge_index = (const int*)d_in[1];      // (2, E)
    const float* pos = (const float*)d_in[2];         // (N, 6)
    const int* batch = (const int*)d_in[3];           // (N,)
    const float* s1 = (const float*)d_in[4];
    const float* s2 = (const float*)d_in[5];
    const float* W1 = (const float*)d_in[6];
    const float* b1 = (const float*)d_in[7];
    const float* W2 = (const float*)d_in[8];
    const float* b2 = (const float*)d_in[9];
    const float* W3 = (const float*)d_in[10];
    const float* b3 = (const float*)d_in[11];
    const float* W4 = (const float*)d_in[12];
    const float* b4 = (const float*)d_in[13];
    const float* g1 = (const float*)d_in[14];
    const float* be1 = (const float*)d_in[15];
    const float* g2 = (const float*)d_in[16];
    const float* be2 = (const float*)d_in[17];
    const float* g3 = (const float*)d_in[18];
    const float* be3 = (const float*)d_in[19];
    const float* Wout = (const float*)d_in[20];
    const float* bout = (const float*)d_in[21];

    const size_t E = (size_t)in_sizes[1] / 2;
    const size_t N = (size_t)in_sizes[3];

    const int* row = edge_index;
    const int* col = edge_index + E;

    auto align256 = [](size_t v) { return (v + 255) & ~(size_t)255; };
    char* w = (char*)d_ws;
    int* rows = (int*)w;     w += align256(E * 4);
    float* norms = (float*)w; w += align256(E * 4);
    float* bufA = (float*)w; w += align256(N * 32 * 4);  // also aliases ew
    float* bufB = (float*)w; w += align256(N * 32 * 4);
    float* dinv = (float*)w; w += align256(N * 4);       // deg then dinv in place
    int* hist = (int*)w;     w += align256(N * 4);
    int* ptr = (int*)w;      w += align256((N + 1) * 4);
    int* cursor = (int*)w;   w += align256(N * 4);
    float* sums = (float*)w; w += align256(256 * 32 * 4);
    float* cnt = (float*)w;  w += align256(256 * 4);
    float* ew = bufA;  // dead after fill_kernel; bufA first written by matmul1 (after fill)

    float* out_emb = (float*)d_out;
    float* out_pred = (float*)d_out + N * 32;

    const int gN = (int)((N + TB - 1) / TB);
    const int gE = (int)((E + TB - 1) / TB);
    const int gN32 = (int)((N * 32 + TB - 1) / TB);

    zero_kernel<<<gN, TB, 0, stream>>>(dinv, hist, sums, cnt, (int)N);
    edge_weight_kernel<<<gE, TB, 0, stream>>>(row, col, (const float2*)pos, s1, s2,
                                              ew, dinv, hist, (int)E);
    dinv_kernel<<<gN, TB, 0, stream>>>(dinv, (int)N);
    scan_kernel<<<1, SCAN_T, 0, stream>>>(hist, ptr, cursor, (int)N);
    fill_kernel<<<gE, TB, 0, stream>>>(row, col, ew, dinv, cursor, rows, norms, (int)E);

    // Layer 1: x (N,6) @ W1 -> bufA; gather -> bufB
    matmul_kernel<6, false><<<gN, TB, 0, stream>>>(x, W1, nullptr, nullptr, bufA, (int)N);
    gather_kernel<false><<<gN32, TB, 0, stream>>>(ptr, rows, norms, bufA, dinv, b1, batch,
                                                  bufB, sums, cnt, (int)N);
    // Layer 2
    matmul_kernel<32, true><<<gN, TB, 0, stream>>>(bufB, W2, g1, be1, bufA, (int)N);
    gather_kernel<false><<<gN32, TB, 0, stream>>>(ptr, rows, norms, bufA, dinv, b2, batch,
                                                  bufB, sums, cnt, (int)N);
    // Layer 3
    matmul_kernel<32, true><<<gN, TB, 0, stream>>>(bufB, W3, g2, be2, bufA, (int)N);
    gather_kernel<false><<<gN32, TB, 0, stream>>>(ptr, rows, norms, bufA, dinv, b3, batch,
                                                  bufB, sums, cnt, (int)N);
    // Layer 4: gather writes emb to d_out and does pooling
    matmul_kernel<32, true><<<gN, TB, 0, stream>>>(bufB, W4, g3, be3, bufA, (int)N);
    gather_kernel<true><<<gN32, TB, 0, stream>>>(ptr, rows, norms, bufA, dinv, b4, batch,
                                                 out_emb, sums, cnt, (int)N);

    pred_kernel<<<1, TB, 0, stream>>>(sums, cnt, Wout, bout, out_pred);
}

// Round 4
// 1443.346 us; speedup vs baseline: 1.3932x; 1.0474x over previous
//
#include <hip/hip_runtime.h>
#include <hip/hip_bf16.h>
#include <math.h>

#define TB 256
#define SCAN_T 1024

__device__ __forceinline__ void atomic_add_f32(float* p, float v) {
    unsafeAtomicAdd(p, v);  // hardware global_atomic_add_f32
}

// Zero deg (N), hist (N), sums (256*32), cnt (256)
__global__ __launch_bounds__(TB) void zero_kernel(float* __restrict__ deg,
                                                  int* __restrict__ hist,
                                                  float* __restrict__ sums,
                                                  float* __restrict__ cnt,
                                                  int n_nodes) {
    int i = blockIdx.x * TB + threadIdx.x;
    if (i < n_nodes) { deg[i] = 0.0f; hist[i] = 0; }
    if (i < 256 * 32) sums[i] = 0.0f;
    if (i < 256) cnt[i] = 0.0f;
}

// Per-edge Gaussian weight + degree scatter + col histogram
__global__ __launch_bounds__(TB) void edge_weight_kernel(
    const int* __restrict__ row, const int* __restrict__ col,
    const float2* __restrict__ pos2,
    const float* __restrict__ s1p, const float* __restrict__ s2p,
    float* __restrict__ ew, float* __restrict__ deg, int* __restrict__ hist,
    int n_edges) {
    int e = blockIdx.x * TB + threadIdx.x;
    if (e >= n_edges) return;
    int r = row[e], c = col[e];
    float2 r0 = pos2[r * 3 + 0], r1 = pos2[r * 3 + 1], r2 = pos2[r * 3 + 2];
    float2 c0 = pos2[c * 3 + 0], c1 = pos2[c * 3 + 1], c2 = pos2[c * 3 + 2];
    float dx = r0.x - c0.x, dy = r0.y - c0.y, dz = r1.x - c1.x;
    float D = dx * dx + dy * dy + dz * dz;
    float dot = r1.y * c1.y + r2.x * c2.x + r2.y * c2.y;
    float t = 1.0f - dot;
    float T = t * t;
    float s1 = s1p[0], s2 = s2p[0];
    float w = expf(-(D * s1 * s1 + T * s2 * s2));
    ew[e] = w;
    atomic_add_f32(&deg[c], w);
    atomicAdd(&hist[c], 1);
}

// dinv = (deg+1)^-0.5, in place
__global__ __launch_bounds__(TB) void dinv_kernel(float* __restrict__ deg, int n) {
    int i = blockIdx.x * TB + threadIdx.x;
    if (i < n) deg[i] = 1.0f / sqrtf(deg[i] + 1.0f);
}

// Single-block exclusive scan: hist[0..n) -> ptr[0..n], cursor copy
__global__ __launch_bounds__(SCAN_T) void scan_kernel(const int* __restrict__ hist,
                                                      int* __restrict__ ptr,
                                                      int* __restrict__ cursor, int n) {
    __shared__ int part[SCAN_T];
    int t = threadIdx.x;
    int chunk = (n + SCAN_T - 1) / SCAN_T;
    int beg = t * chunk;
    int end = min(beg + chunk, n);
    int s = 0;
    for (int i = beg; i < end; i++) s += hist[i];
    part[t] = s;
    __syncthreads();
    for (int off = 1; off < SCAN_T; off <<= 1) {
        int v = (t >= off) ? part[t - off] : 0;
        __syncthreads();
        part[t] += v;
        __syncthreads();
    }
    int run = (t == 0) ? 0 : part[t - 1];
    for (int i = beg; i < end; i++) {
        ptr[i] = run;
        cursor[i] = run;
        run += hist[i];
    }
    if (t == SCAN_T - 1) ptr[n] = part[SCAN_T - 1];
}

// Scatter edges into CSR slots; split arrays: rows[] and norms[]
__global__ __launch_bounds__(TB) void fill_kernel(
    const int* __restrict__ row, const int* __restrict__ col,
    const float* __restrict__ ew, const float* __restrict__ dinv,
    int* __restrict__ cursor, int* __restrict__ rows, float* __restrict__ norms,
    int n_edges) {
    int e = blockIdx.x * TB + threadIdx.x;
    if (e >= n_edges) return;
    int r = row[e], c = col[e];
    float nm = dinv[r] * ew[e] * dinv[c];
    int pos = atomicAdd(&cursor[c], 1);
    rows[pos] = r;
    norms[pos] = nm;
}

// Dense matmul fin(N x K) @ W(K x 32) -> xw(N x 32); optional fused BN+ReLU on input
template <int K, bool BN>
__global__ __launch_bounds__(TB) void matmul_kernel(
    const float* __restrict__ fin, const float* __restrict__ W,
    const float* __restrict__ g, const float* __restrict__ be,
    float* __restrict__ xw, int n_nodes) {
    __shared__ float Ws[K * 32];
    __shared__ float gs[32];
    __shared__ float bs[32];
    int tid = threadIdx.x;
    for (int i = tid; i < K * 32; i += TB) Ws[i] = W[i];
    if (BN) {
        if (tid < 32) {
            gs[tid] = g[tid] * (1.0f / sqrtf(1.0f + 1e-5f));
            bs[tid] = be[tid];
        }
    }
    __syncthreads();
    int n = blockIdx.x * TB + tid;
    if (n >= n_nodes) return;
    float vals[K];
    const float* fp = fin + (size_t)n * K;
    if (K % 4 == 0) {
#pragma unroll
        for (int k = 0; k < K / 4; k++) {
            float4 v = ((const float4*)fp)[k];
            vals[k * 4 + 0] = v.x;
            vals[k * 4 + 1] = v.y;
            vals[k * 4 + 2] = v.z;
            vals[k * 4 + 3] = v.w;
        }
    } else {
#pragma unroll
        for (int k = 0; k < K; k++) vals[k] = fp[k];
    }
    if (BN) {
#pragma unroll
        for (int k = 0; k < K; k++) vals[k] = fmaxf(fmaf(vals[k], gs[k], bs[k]), 0.0f);
    }
    float acc[32];
#pragma unroll
    for (int j = 0; j < 32; j++) acc[j] = 0.0f;
#pragma unroll
    for (int k = 0; k < K; k++) {
        float v = vals[k];
#pragma unroll
        for (int j = 0; j < 32; j++) acc[j] = fmaf(v, Ws[k * 32 + j], acc[j]);
    }
    float4* op = (float4*)(xw + (size_t)n * 32);
#pragma unroll
    for (int j = 0; j < 8; j++)
        op[j] = make_float4(acc[j * 4], acc[j * 4 + 1], acc[j * 4 + 2], acc[j * 4 + 3]);
}

__device__ __forceinline__ float4 f4_fma(float w, float4 v, float4 a) {
    return make_float4(fmaf(w, v.x, a.x), fmaf(w, v.y, a.y),
                       fmaf(w, v.z, a.z), fmaf(w, v.w, a.w));
}

// Per-node gather: 8 lanes per node, each lane owns a float4 of features.
// Edge loop unrolled x8: 8 independent 1KiB gather instructions in flight.
// agg[n] = b + dinv[n]^2*xw[n] + sum_e norm_e * xw[row_e]
template <bool POOL>
__global__ __launch_bounds__(TB) void gather_kernel(
    const int* __restrict__ ptr, const int* __restrict__ rows,
    const float* __restrict__ norms,
    const float4* __restrict__ xw4, const float* __restrict__ dinv,
    const float4* __restrict__ b4, const int* __restrict__ batch,
    float4* __restrict__ agg4, float* __restrict__ sums, float* __restrict__ cnt,
    int n_nodes) {
    int t = blockIdx.x * TB + threadIdx.x;
    int n = t >> 3, f = t & 7;
    if (n >= n_nodes) return;
    int beg = ptr[n], end = ptr[n + 1];
    float4 acc = make_float4(0.f, 0.f, 0.f, 0.f);
    int k = beg;
    for (; k + 8 <= end; k += 8) {
        // 8 edge indices + weights (32B streams, broadcast within octet)
        int4 ra = ((const int4*)(rows + k))[0];
        int4 rb = ((const int4*)(rows + k))[1];
        float4 wa = ((const float4*)(norms + k))[0];
        float4 wb = ((const float4*)(norms + k))[1];
        // 8 independent float4 gathers (each instr: 16B/lane x 64 lanes = 1KiB)
        float4 v0 = xw4[(size_t)ra.x * 8 + f];
        float4 v1 = xw4[(size_t)ra.y * 8 + f];
        float4 v2 = xw4[(size_t)ra.z * 8 + f];
        float4 v3 = xw4[(size_t)ra.w * 8 + f];
        float4 v4 = xw4[(size_t)rb.x * 8 + f];
        float4 v5 = xw4[(size_t)rb.y * 8 + f];
        float4 v6 = xw4[(size_t)rb.z * 8 + f];
        float4 v7 = xw4[(size_t)rb.w * 8 + f];
        acc = f4_fma(wa.x, v0, acc);
        acc = f4_fma(wa.y, v1, acc);
        acc = f4_fma(wa.z, v2, acc);
        acc = f4_fma(wa.w, v3, acc);
        acc = f4_fma(wb.x, v4, acc);
        acc = f4_fma(wb.y, v5, acc);
        acc = f4_fma(wb.z, v6, acc);
        acc = f4_fma(wb.w, v7, acc);
    }
    for (; k < end; k++) {
        int r = rows[k];
        float wv = norms[k];
        acc = f4_fma(wv, xw4[(size_t)r * 8 + f], acc);
    }
    float di = dinv[n];
    float4 self = xw4[(size_t)n * 8 + f];
    float4 bb = b4[f];
    float4 v;
    v.x = fmaf(di * di, self.x, acc.x) + bb.x;
    v.y = fmaf(di * di, self.y, acc.y) + bb.y;
    v.z = fmaf(di * di, self.z, acc.z) + bb.z;
    v.w = fmaf(di * di, self.w, acc.w) + bb.w;
    agg4[(size_t)n * 8 + f] = v;
    if (POOL) {
        int bg = batch[n];
        float* sp = sums + (size_t)bg * 32 + f * 4;
        atomic_add_f32(sp + 0, v.x);
        atomic_add_f32(sp + 1, v.y);
        atomic_add_f32(sp + 2, v.z);
        atomic_add_f32(sp + 3, v.w);
        if (f == 0) atomic_add_f32(&cnt[bg], 1.0f);
    }
}

// pred[g] = sigmoid(dot(sums[g]/max(cnt,1), Wout) + bout)
__global__ __launch_bounds__(TB) void pred_kernel(
    const float* __restrict__ sums, const float* __restrict__ cnt,
    const float* __restrict__ Wout, const float* __restrict__ bout,
    float* __restrict__ out) {
    int g = blockIdx.x * TB + threadIdx.x;
    if (g >= 256) return;
    float c = fmaxf(cnt[g], 1.0f);
    float acc = 0.0f;
#pragma unroll
    for (int j = 0; j < 32; j++) acc += sums[g * 32 + j] * Wout[j];
    float z = acc / c + bout[0];
    out[g] = 1.0f / (1.0f + expf(-z));
}

extern "C" void kernel_launch(void* const* d_in, const int* in_sizes, int n_in,
                              void* d_out, int out_size, void* d_ws, size_t ws_size,
                              hipStream_t stream) {
    const float* x = (const float*)d_in[0];           // (N, 6)
    const int* edge_index = (const int*)d_in[1];      // (2, E)
    const float* pos = (const float*)d_in[2];         // (N, 6)
    const int* batch = (const int*)d_in[3];           // (N,)
    const float* s1 = (const float*)d_in[4];
    const float* s2 = (const float*)d_in[5];
    const float* W1 = (const float*)d_in[6];
    const float* b1 = (const float*)d_in[7];
    const float* W2 = (const float*)d_in[8];
    const float* b2 = (const float*)d_in[9];
    const float* W3 = (const float*)d_in[10];
    const float* b3 = (const float*)d_in[11];
    const float* W4 = (const float*)d_in[12];
    const float* b4 = (const float*)d_in[13];
    const float* g1 = (const float*)d_in[14];
    const float* be1 = (const float*)d_in[15];
    const float* g2 = (const float*)d_in[16];
    const float* be2 = (const float*)d_in[17];
    const float* g3 = (const float*)d_in[18];
    const float* be3 = (const float*)d_in[19];
    const float* Wout = (const float*)d_in[20];
    const float* bout = (const float*)d_in[21];

    const size_t E = (size_t)in_sizes[1] / 2;
    const size_t N = (size_t)in_sizes[3];

    const int* row = edge_index;
    const int* col = edge_index + E;

    auto align256 = [](size_t v) { return (v + 255) & ~(size_t)255; };
    char* w = (char*)d_ws;
    int* rows = (int*)w;     w += align256(E * 4);
    float* norms = (float*)w; w += align256(E * 4);
    float* bufA = (float*)w; w += align256(N * 32 * 4);  // also aliases ew
    float* bufB = (float*)w; w += align256(N * 32 * 4);
    float* dinv = (float*)w; w += align256(N * 4);       // deg then dinv in place
    int* hist = (int*)w;     w += align256(N * 4);
    int* ptr = (int*)w;      w += align256((N + 1) * 4);
    int* cursor = (int*)w;   w += align256(N * 4);
    float* sums = (float*)w; w += align256(256 * 32 * 4);
    float* cnt = (float*)w;  w += align256(256 * 4);
    float* ew = bufA;  // dead after fill_kernel; bufA first written by matmul1 (after fill)

    float* out_emb = (float*)d_out;
    float* out_pred = (float*)d_out + N * 32;

    const int gN = (int)((N + TB - 1) / TB);
    const int gE = (int)((E + TB - 1) / TB);
    const int gN8 = (int)((N * 8 + TB - 1) / TB);

    zero_kernel<<<gN, TB, 0, stream>>>(dinv, hist, sums, cnt, (int)N);
    edge_weight_kernel<<<gE, TB, 0, stream>>>(row, col, (const float2*)pos, s1, s2,
                                              ew, dinv, hist, (int)E);
    dinv_kernel<<<gN, TB, 0, stream>>>(dinv, (int)N);
    scan_kernel<<<1, SCAN_T, 0, stream>>>(hist, ptr, cursor, (int)N);
    fill_kernel<<<gE, TB, 0, stream>>>(row, col, ew, dinv, cursor, rows, norms, (int)E);

    // Layer 1: x (N,6) @ W1 -> bufA; gather -> bufB
    matmul_kernel<6, false><<<gN, TB, 0, stream>>>(x, W1, nullptr, nullptr, bufA, (int)N);
    gather_kernel<false><<<gN8, TB, 0, stream>>>(ptr, rows, norms, (const float4*)bufA,
                                                 dinv, (const float4*)b1, batch,
                                                 (float4*)bufB, sums, cnt, (int)N);
    // Layer 2
    matmul_kernel<32, true><<<gN, TB, 0, stream>>>(bufB, W2, g1, be1, bufA, (int)N);
    gather_kernel<false><<<gN8, TB, 0, stream>>>(ptr, rows, norms, (const float4*)bufA,
                                                 dinv, (const float4*)b2, batch,
                                                 (float4*)bufB, sums, cnt, (int)N);
    // Layer 3
    matmul_kernel<32, true><<<gN, TB, 0, stream>>>(bufB, W3, g2, be2, bufA, (int)N);
    gather_kernel<false><<<gN8, TB, 0, stream>>>(ptr, rows, norms, (const float4*)bufA,
                                                 dinv, (const float4*)b3, batch,
                                                 (float4*)bufB, sums, cnt, (int)N);
    // Layer 4: gather writes emb to d_out and does pooling
    matmul_kernel<32, true><<<gN, TB, 0, stream>>>(bufB, W4, g3, be3, bufA, (int)N);
    gather_kernel<true><<<gN8, TB, 0, stream>>>(ptr, rows, norms, (const float4*)bufA,
                                                dinv, (const float4*)b4, batch,
                                                (float4*)out_emb, sums, cnt, (int)N);

    pred_kernel<<<1, TB, 0, stream>>>(sums, cnt, Wout, bout, out_pred);
}